// Round 6
// baseline (433.906 us; speedup 1.0000x reference)
//
#include <hip/hip_runtime.h>
#include <hip/hip_bf16.h>

// Problem constants (R=4096, S=128, V=3, F=35)
#define NPTS      524288            // R*S
#define OUT2_BASE 4718592           // NPTS*9  (rgb_in elements)
#define NBLK64    8192              // NPTS/64

using bf16x8 = __attribute__((ext_vector_type(8))) short;   // MFMA A/B frag
using f32x4  = __attribute__((ext_vector_type(4))) float;   // MFMA C/D frag

#define MFMA(a, b, c) __builtin_amdgcn_mfma_f32_16x16x32_bf16(a, b, c, 0, 0, 0)

// Weight workspace (ushort/bf16 in d_ws), [N][K] row-major, K padded, pads ZEROED:
//   WG [64][96]  @ 0      = bw1 mean part at cols 0..34, VAR part at cols 40..74
//                           (cols 35..39, 75..95 = 0)
//   WF [64][72]  @ 6144   = bw1[:, 70:105](view part),  cols 35..71 = 0
//   W2 [32][72]  @ 10752  = bw2,  cols 64..71 = 0
//   V1 [32][40]  @ 13056  = vw1/3 (x/num_views folded), cols 32..39 = 0
//   V2 [32][40]  @ 14336  = vw2,  cols 32..39 = 0
//   R1 [32][104] @ 15616  = rw1,  cols 96..103 = 0
//   R2 [16][40]  @ 18944  = rw2,  cols 32..39 = 0

__device__ __forceinline__ ushort f2bf(float f) {
    union { float f; unsigned u; } v; v.f = f;
    unsigned u = v.u;
    unsigned r = u + 0x7fffu + ((u >> 16) & 1u);   // RTNE
    return (ushort)(r >> 16);
}
__device__ __forceinline__ uint pack2(float a, float b) {   // lo=bf16(a), hi=bf16(b)
    union { __hip_bfloat162 h; uint u; } cv;
    cv.h = __float22bfloat162_rn(make_float2(a, b));
    return cv.u;
}
__device__ __forceinline__ float eluf(float x) {
    return fmaxf(x, 0.f) + __expf(fminf(x, 0.f)) - 1.f;
}
__device__ __forceinline__ float sigm(float x) { return 1.f / (1.f + __expf(-x)); }

// unaligned-safe 8-float load (feat rows are 105 floats -> only 4B-aligned)
__device__ __forceinline__ void load8(const float* __restrict__ p, float* d) {
    __builtin_memcpy(d, p, 16);
    __builtin_memcpy(d + 4, p + 4, 16);
}
__device__ __forceinline__ bf16x8 pk8(const float* x) {     // 8 f32 -> bf16x8
    union { uint4 u; bf16x8 h; } cv;
    cv.u = make_uint4(pack2(x[0], x[1]), pack2(x[2], x[3]),
                      pack2(x[4], x[5]), pack2(x[6], x[7]));
    return cv.h;
}
__device__ __forceinline__ bf16x8 pk4u(uint a, uint b, uint c, uint d) {
    union { uint4 u; bf16x8 h; } cv;
    cv.u = make_uint4(a, b, c, d);
    return cv.h;
}
__device__ __forceinline__ bf16x8 ldw(const ushort* p) { return *(const bf16x8*)p; }

__global__ void prep_k(const float* __restrict__ bw1, const float* __restrict__ bw2,
                       const float* __restrict__ vw1, const float* __restrict__ vw2,
                       const float* __restrict__ rw1, const float* __restrict__ rw2,
                       ushort* __restrict__ w)
{
    int i = blockIdx.x * 256 + threadIdx.x;
    if (i < 6144) {                                   // WG [64][96] mean@0..34, var@40..74
        int n = i / 96, k = i % 96;
        float val = 0.f;
        if (k < 35)                 val = bw1[n * 105 + k];
        else if (k >= 40 && k < 75) val = bw1[n * 105 + 35 + (k - 40)];
        w[i] = f2bf(val);
    } else if (i < 10752) {                           // WF [64][72]
        int t = i - 6144, n = t / 72, k = t % 72;
        w[i] = f2bf(k < 35 ? bw1[n * 105 + 70 + k] : 0.f);
    } else if (i < 13056) {                           // W2 [32][72]
        int t = i - 10752, n = t / 72, k = t % 72;
        w[i] = f2bf(k < 64 ? bw2[n * 64 + k] : 0.f);
    } else if (i < 14336) {                           // V1 [32][40] (/3 folded)
        int t = i - 13056, n = t / 40, k = t % 40;
        w[i] = f2bf(k < 32 ? vw1[n * 32 + k] * (1.f / 3.f) : 0.f);
    } else if (i < 15616) {                           // V2 [32][40]
        int t = i - 14336, n = t / 40, k = t % 40;
        w[i] = f2bf(k < 32 ? vw2[n * 32 + k] : 0.f);
    } else if (i < 18944) {                           // R1 [32][104]
        int t = i - 15616, n = t / 104, k = t % 104;
        w[i] = f2bf(k < 96 ? rw1[n * 96 + k] : 0.f);
    } else if (i < 19584) {                           // R2 [16][40]
        int t = i - 18944, n = t / 40, k = t % 40;
        w[i] = f2bf(k < 32 ? rw2[n * 32 + k] : 0.f);
    }
}

// WAVE-INDEPENDENT kernel: ZERO barriers. 4 waves/block (256 thr), each wave owns
// 16 points end-to-end; 64 pts/block, 8192 blocks. Lane (n16=point, quad=k-chunk).
// X built IN-REGISTER from global (per-lane loads = exactly its B-frag's 8 floats);
// the two cross-quad var frags (Xg ks1/ks2) via 8 ds_bpermute + selects.
// All layer transitions through WAVE-PRIVATE LDS (per-wave DS ops execute in order;
// compiler lgkmcnt handles RAW) -- no inter-wave coupling anywhere.
// TRANSPOSED-C: mfma(W,X) -> lane holds 4 consecutive feats of point n16; stores are
// one uint2 into XOR-swizzled 16B slots (slot ^= n16&7 for 128B rows, n16&3 else).
// Per-wave LDS 9216 B, timeline-aliased:
//   RA 6144 B: h1[3][16][64] -> t1[3][16][32] -> r1[16][32]
//   RB 3072 B: h2[3][16][32] -> x2[16][96]
// Cg folded into Cf accumulation as MFMA C-input (saves the adds).
__global__ __launch_bounds__(256, 4) void mlp_k(
    const float* __restrict__ feat, const ushort* __restrict__ w,
    const float* __restrict__ bb1, const float* __restrict__ bb2,
    const float* __restrict__ vb1, const float* __restrict__ vb2,
    const float* __restrict__ rb1, const float* __restrict__ rb2,
    const float* __restrict__ rw3, const float* __restrict__ rb3,
    float* __restrict__ out)
{
    __shared__ __align__(16) ushort sh[4][4608];      // 9216 B per wave

    const int tid  = threadIdx.x;
    const int wave = tid >> 6;
    const int lane = tid & 63;
    const int n16  = lane & 15;         // point within wave tile
    const int quad = lane >> 4;         // k-chunk / feature-quad
    char* const RA = (char*)sh[wave];          // 6144 B
    char* const RB = (char*)sh[wave] + 6144;   // 3072 B
    const int sw7 = n16 & 7;            // swizzle for 128B rows (8 slots)
    const int sw3 = n16 & 3;            // swizzle for 64/192B rows

    const long long pbase = (long long)blockIdx.x * 64 + wave * 16;
    const long long pt    = pbase + n16;
    const float* row = feat + pt * 105;

    const ushort* WG = w;
    const ushort* WF = w + 6144;
    const ushort* W2 = w + 10752;
    const ushort* V1 = w + 13056;
    const ushort* V2 = w + 14336;
    const ushort* R1 = w + 15616;
    const ushort* R2 = w + 18944;

    // ---- rgb_in passthrough (fp32 exact): 16 pts x 9 per wave ----
    {
        float* o1 = out + pbase * 9;
        const float* f0 = feat + pbase * 105;
#pragma unroll
        for (int t = 0; t < 3; ++t) {
            int i = lane + t * 64;
            if (t < 2 || lane < 16) {
                int p = i / 9, r = i - p * 9, v = r / 3, c = r - v * 3;
                o1[i] = f0[p * 105 + v * 35 + c];
            }
        }
    }

    // ---- build X in registers: lane loads its own B-frag floats ----
    float A0[8], A1[8], A2[8];
    load8(row + 8 * quad,      A0);     // view 0, feats 8q..8q+7
    load8(row + 35 + 8 * quad, A1);     // view 1
    load8(row + 70 + 8 * quad, A2);     // view 2 (max idx 70+31 = 101 < 105)
    float E0[8] = {0,0,0,0,0,0,0,0}, E1[8] = {0,0,0,0,0,0,0,0}, E2[8] = {0,0,0,0,0,0,0,0};
    if (quad == 0) {                    // feats 32..39 (35..39 garbage x zero weight)
        load8(row + 32, E0);
        load8(row + 67, E1);
        if (pt == (long long)NPTS - 1) {   // guard: row+102+7 runs off the array
            E2[0] = row[102]; E2[1] = row[103]; E2[2] = row[104];
        } else {
            load8(row + 102, E2);
        }
    }
    float M[8], Vv[8], M4[8], V4[8];
#pragma unroll
    for (int j = 0; j < 8; ++j) {
        float a = A0[j], b = A1[j], c = A2[j];
        float m = (a + b + c) * (1.f / 3.f);
        float da = a - m, db = b - m, dc = c - m;
        M[j] = m; Vv[j] = (da * da + db * db + dc * dc) * (1.f / 3.f);
        float a4 = E0[j], b4 = E1[j], c4 = E2[j];
        float m4 = (a4 + b4 + c4) * (1.f / 3.f);
        float e4 = a4 - m4, f4 = b4 - m4, g4 = c4 - m4;
        M4[j] = m4; V4[j] = (e4 * e4 + f4 * f4 + g4 * g4) * (1.f / 3.f);
    }
    uint vPK[4], v4PK[4], m4PK[4];
#pragma unroll
    for (int i = 0; i < 4; ++i) {
        vPK[i]  = pack2(Vv[2 * i], Vv[2 * i + 1]);
        v4PK[i] = pack2(V4[2 * i], V4[2 * i + 1]);
        m4PK[i] = pack2(M4[2 * i], M4[2 * i + 1]);
    }
    // Xf frags: ks0 = own A chunk; ks1 = quad0's E chunk, zeros elsewhere
    bf16x8 XAv[3], XBv[3];
    XAv[0] = pk8(A0); XAv[1] = pk8(A1); XAv[2] = pk8(A2);
    const bf16x8 ZF = pk4u(0u, 0u, 0u, 0u);
    XBv[0] = ZF; XBv[1] = ZF; XBv[2] = ZF;
    if (quad == 0) { XBv[0] = pk8(E0); XBv[1] = pk8(E1); XBv[2] = pk8(E2); }
    // Xg frags: G0 = mean (own); G1 = k 32..63 (q0: mean tail; q>=1: var of quad-1);
    //           G2 = k 64..95 (q0: var of quad3; q1: var tail of quad0; q>=2: 0)
    const bf16x8 G0 = pk8(M);
    const int prevAddr = ((lane + 48) & 63) * 4;   // cyclic previous quad, same n16
    uint G1u[4], G2u[4];
#pragma unroll
    for (int i = 0; i < 4; ++i) {
        uint bv  = (uint)__builtin_amdgcn_ds_bpermute(prevAddr, (int)vPK[i]);
        uint bv4 = (uint)__builtin_amdgcn_ds_bpermute(prevAddr, (int)v4PK[i]);
        G1u[i] = (quad == 0) ? m4PK[i] : bv;
        G2u[i] = (quad == 0) ? bv : ((quad == 1) ? bv4 : 0u);
    }
    const bf16x8 G1 = pk4u(G1u[0], G1u[1], G1u[2], G1u[3]);
    const bf16x8 G2 = pk4u(G2u[0], G2u[1], G2u[2], G2u[3]);

    const f32x4 Z = {0.f, 0.f, 0.f, 0.f};

    // ---- layer 1: N=64 (4 ntl tiles), Cg seeded as C-input of Cf chain ----
#pragma unroll
    for (int ntl = 0; ntl < 4; ++ntl) {
        const ushort* WGb = WG + (ntl * 16 + n16) * 96 + quad * 8;
        f32x4 Cg = MFMA(ldw(WGb), G0, Z);
        Cg = MFMA(ldw(WGb + 32), G1, Cg);
        Cg = MFMA(ldw(WGb + 64), G2, Cg);
        const ushort* WFb = WF + (ntl * 16 + n16) * 72 + quad * 8;
        const bf16x8 wf0 = ldw(WFb), wf1 = ldw(WFb + 32);
        const float4 bq = *(const float4*)(bb1 + ntl * 16 + quad * 4);
#pragma unroll
        for (int v = 0; v < 3; ++v) {
            f32x4 C = MFMA(wf0, XAv[v], Cg);          // Cg folded in as C-in
            C = MFMA(wf1, XBv[v], C);
            float e0 = eluf(C[0] + bq.x), e1 = eluf(C[1] + bq.y);
            float e2 = eluf(C[2] + bq.z), e3 = eluf(C[3] + bq.w);
            uint2 u; u.x = pack2(e0, e1); u.y = pack2(e2, e3);
            int slot = (ntl * 2 + (quad >> 1)) ^ sw7;
            *(uint2*)(RA + v * 2048 + n16 * 128 + slot * 16 + (quad & 1) * 8) = u;
        }
    }

    // ---- layer 2: N=32, K=64 from h1 (wave-private LDS, in-order DS) ----
    float h2r[3][2][4];
#pragma unroll
    for (int v = 0; v < 3; ++v) {
        const bf16x8 ha = *(const bf16x8*)(RA + v * 2048 + n16 * 128 + ((0 + quad) ^ sw7) * 16);
        const bf16x8 hb = *(const bf16x8*)(RA + v * 2048 + n16 * 128 + ((4 + quad) ^ sw7) * 16);
#pragma unroll
        for (int n2 = 0; n2 < 2; ++n2) {
            const ushort* W2b = W2 + (n2 * 16 + n16) * 72 + quad * 8;
            f32x4 C = MFMA(ldw(W2b), ha, Z);
            C = MFMA(ldw(W2b + 32), hb, C);
            const float4 bq = *(const float4*)(bb2 + n2 * 16 + quad * 4);
            float e0 = eluf(C[0] + bq.x), e1 = eluf(C[1] + bq.y);
            float e2 = eluf(C[2] + bq.z), e3 = eluf(C[3] + bq.w);
            h2r[v][n2][0] = e0; h2r[v][n2][1] = e1;
            h2r[v][n2][2] = e2; h2r[v][n2][3] = e3;
            uint2 u; u.x = pack2(e0, e1); u.y = pack2(e2, e3);
            int slot = (n2 * 2 + (quad >> 1)) ^ sw3;
            *(uint2*)(RB + v * 1024 + n16 * 64 + slot * 16 + (quad & 1) * 8) = u;
        }
    }

    // ---- vis layer 1: t1 = elu(V1 @ h2) -> RA (h1 dead after L2 reads) ----
#pragma unroll
    for (int v = 0; v < 3; ++v) {
        const bf16x8 hf = *(const bf16x8*)(RB + v * 1024 + n16 * 64 + ((quad ^ sw3) * 16));
#pragma unroll
        for (int n2 = 0; n2 < 2; ++n2) {
            f32x4 C = MFMA(ldw(V1 + (n2 * 16 + n16) * 40 + quad * 8), hf, Z);
            const float4 bq = *(const float4*)(vb1 + n2 * 16 + quad * 4);
            float e0 = eluf(C[0] + bq.x), e1 = eluf(C[1] + bq.y);
            float e2 = eluf(C[2] + bq.z), e3 = eluf(C[3] + bq.w);
            uint2 u; u.x = pack2(e0, e1); u.y = pack2(e2, e3);
            int slot = (n2 * 2 + (quad >> 1)) ^ sw3;
            *(uint2*)(RA + v * 1024 + n16 * 64 + slot * 16 + (quad & 1) * 8) = u;
        }
    }

    // ---- vis layer 2 + residual: x2 = h2 + elu(V2 @ t1) -> RB [16][96] ----
#pragma unroll
    for (int v = 0; v < 3; ++v) {
        const bf16x8 tf = *(const bf16x8*)(RA + v * 1024 + n16 * 64 + ((quad ^ sw3) * 16));
#pragma unroll
        for (int n2 = 0; n2 < 2; ++n2) {
            f32x4 C = MFMA(ldw(V2 + (n2 * 16 + n16) * 40 + quad * 8), tf, Z);
            const float4 bq = *(const float4*)(vb2 + n2 * 16 + quad * 4);
            float x0 = h2r[v][n2][0] + eluf(C[0] + bq.x);
            float x1 = h2r[v][n2][1] + eluf(C[1] + bq.y);
            float x2v = h2r[v][n2][2] + eluf(C[2] + bq.z);
            float x3 = h2r[v][n2][3] + eluf(C[3] + bq.w);
            uint2 u; u.x = pack2(x0, x1); u.y = pack2(x2v, x3);
            int slot = (4 * v + 2 * n2 + (quad >> 1)) ^ sw3;      // feat = 32v+16n2+4q
            *(uint2*)(RB + n16 * 192 + slot * 16 + (quad & 1) * 8) = u;
        }
    }

    // ---- r1 = elu(R1 @ x2), K=96 (ks == view) -> RA[0..1024) ----
    f32x4 CR[2] = {Z, Z};
#pragma unroll
    for (int v = 0; v < 3; ++v) {
        const bf16x8 xf = *(const bf16x8*)(RB + n16 * 192 + (((4 * v + quad) ^ sw3) * 16));
#pragma unroll
        for (int n2 = 0; n2 < 2; ++n2)
            CR[n2] = MFMA(ldw(R1 + (n2 * 16 + n16) * 104 + v * 32 + quad * 8), xf, CR[n2]);
    }
#pragma unroll
    for (int n2 = 0; n2 < 2; ++n2) {
        const float4 bq = *(const float4*)(rb1 + n2 * 16 + quad * 4);
        float e0 = eluf(CR[n2][0] + bq.x), e1 = eluf(CR[n2][1] + bq.y);
        float e2 = eluf(CR[n2][2] + bq.z), e3 = eluf(CR[n2][3] + bq.w);
        uint2 u; u.x = pack2(e0, e1); u.y = pack2(e2, e3);
        int slot = (n2 * 2 + (quad >> 1)) ^ sw3;
        *(uint2*)(RA + n16 * 64 + slot * 16 + (quad & 1) * 8) = u;
    }

    // ---- r2 = elu(R2 @ r1), N=16, K=32 ----
    const bf16x8 rf = *(const bf16x8*)(RA + n16 * 64 + ((quad ^ sw3) * 16));
    f32x4 C3 = MFMA(ldw(R2 + n16 * 40 + quad * 8), rf, Z);
    const float4 bq2 = *(const float4*)(rb2 + quad * 4);
    float r0 = eluf(C3[0] + bq2.x), r1v = eluf(C3[1] + bq2.y);
    float r2v = eluf(C3[2] + bq2.z), r3 = eluf(C3[3] + bq2.w);

    // ---- final 16 -> 3 + sigmoid: in-register, quad-reduce via shfl_xor ----
    const float4 w30 = *(const float4*)(rw3 + 0 * 16 + quad * 4);
    const float4 w31 = *(const float4*)(rw3 + 1 * 16 + quad * 4);
    const float4 w32 = *(const float4*)(rw3 + 2 * 16 + quad * 4);
    float s0 = r0 * w30.x + r1v * w30.y + r2v * w30.z + r3 * w30.w;
    float s1 = r0 * w31.x + r1v * w31.y + r2v * w31.z + r3 * w31.w;
    float s2 = r0 * w32.x + r1v * w32.y + r2v * w32.z + r3 * w32.w;
    s0 += __shfl_xor(s0, 16); s0 += __shfl_xor(s0, 32);
    s1 += __shfl_xor(s1, 16); s1 += __shfl_xor(s1, 32);
    s2 += __shfl_xor(s2, 16); s2 += __shfl_xor(s2, 32);
    if (quad == 0) {
        float* o2 = out + OUT2_BASE + pt * 3;
        o2[0] = sigm(s0 + rb3[0]);
        o2[1] = sigm(s1 + rb3[1]);
        o2[2] = sigm(s2 + rb3[2]);
    }
}

extern "C" void kernel_launch(void* const* d_in, const int* in_sizes, int n_in,
                              void* d_out, int out_size, void* d_ws, size_t ws_size,
                              hipStream_t stream) {
    const float* feat = (const float*)d_in[0];
    const float* bw1  = (const float*)d_in[1];
    const float* bb1  = (const float*)d_in[2];
    const float* bw2  = (const float*)d_in[3];
    const float* bb2  = (const float*)d_in[4];
    const float* vw1  = (const float*)d_in[5];
    const float* vb1  = (const float*)d_in[6];
    const float* vw2  = (const float*)d_in[7];
    const float* vb2  = (const float*)d_in[8];
    const float* rw1  = (const float*)d_in[9];
    const float* rb1  = (const float*)d_in[10];
    const float* rw2  = (const float*)d_in[11];
    const float* rb2  = (const float*)d_in[12];
    const float* rw3  = (const float*)d_in[13];
    const float* rb3  = (const float*)d_in[14];
    ushort* w  = (ushort*)d_ws;
    float* out = (float*)d_out;

    hipLaunchKernelGGL(prep_k, dim3(77), dim3(256), 0, stream,
                       bw1, bw2, vw1, vw2, rw1, rw2, w);
    hipLaunchKernelGGL(mlp_k, dim3(NBLK64), dim3(256), 0, stream,
                       feat, w, bb1, bb2, vb1, vb2, rb1, rb2, rw3, rb3, out);
}